// Round 1
// 284.482 us; speedup vs baseline: 1.0774x; 1.0774x over previous
//
#include <hip/hip_runtime.h>

#define IN_DIM   128
#define NH       8
#define HD       16
#define OUTD     128   // NH*HD
#define QKVD     384   // Q|K|V per node, bf16

typedef unsigned short ushort_t;
typedef unsigned int   uint_t;
typedef __bf16 bf16x8 __attribute__((ext_vector_type(8)));
typedef float  f32x4  __attribute__((ext_vector_type(4)));
typedef unsigned short us4 __attribute__((ext_vector_type(4)));

__device__ __forceinline__ float bf2f(ushort_t u) {
    return __uint_as_float(((uint_t)u) << 16);
}
__device__ __forceinline__ ushort_t f2bf(float f) {
    uint_t u = __float_as_uint(f);
    u += 0x7FFFu + ((u >> 16) & 1u);      // RNE
    return (ushort_t)(u >> 16);
}

// ---------------------------------------------------------------------------
// prep_w: W[k][c] fp32 (3 mats) -> Wt[col][k] bf16, col in [0,384).
// Also zeroes P[N] and desc[128].
// ---------------------------------------------------------------------------
__global__ __launch_bounds__(256) void prep_w(
    const float* __restrict__ Wq, const float* __restrict__ Wk,
    const float* __restrict__ Wv, ushort_t* __restrict__ Wt,
    int* __restrict__ P, unsigned long long* __restrict__ desc, int N)
{
    __shared__ float ld[32][33];
    int mat  = blockIdx.x >> 4;
    int tile = blockIdx.x & 15;
    int k0 = (tile >> 2) * 32, c0 = (tile & 3) * 32;
    const float* W = (mat == 0) ? Wq : (mat == 1) ? Wk : Wv;
    int t = threadIdx.x;
    {
        int k = t >> 3, c4 = (t & 7) * 4;
        float4 f = *(const float4*)&W[(size_t)(k0 + k) * 128 + c0 + c4];
        ld[k][c4 + 0] = f.x; ld[k][c4 + 1] = f.y;
        ld[k][c4 + 2] = f.z; ld[k][c4 + 3] = f.w;
    }
    __syncthreads();
    {
        int c = t >> 3, kg = (t & 7) * 4;
        union { ushort_t h[4]; uint2 u; } o;
        o.h[0] = f2bf(ld[kg + 0][c]); o.h[1] = f2bf(ld[kg + 1][c]);
        o.h[2] = f2bf(ld[kg + 2][c]); o.h[3] = f2bf(ld[kg + 3][c]);
        *(uint2*)&Wt[((size_t)(mat * 128 + c0 + c)) * 128 + k0 + kg] = o.u;
    }
    int t0 = blockIdx.x * 256 + threadIdx.x;
    for (int i = t0; i < N; i += 48 * 256) P[i] = 0;
    if (t0 < 128) desc[t0] = 0ULL;
}

// ---------------------------------------------------------------------------
// gemm_rank (persistent): 512 blocks x 384 thr (2 blocks/CU, 3 waves/SIMD).
// Prologue: single atomic pass — histogram WITH return value; the return is
// the edge's rank within its dst bucket (stored coalesced as ushort). This
// replaces scatter's second 800k-atomic pass entirely.
// Then each wave loads its 16 B-fragments from Wt ONCE (64 VGPRs) and the
// block grid-strides over 64-row tiles: stage A in LDS (k-packed, 65-pad),
// 64 MFMAs/wave, epilogue LDS-transpose in 4 quarters -> coalesced dwordx4
// stores to qkv[N][384] bf16.
// ---------------------------------------------------------------------------
__global__ __launch_bounds__(384, 3) void gemm_rank(
    const float* __restrict__ x, const ushort_t* __restrict__ Wt,
    const float* __restrict__ bq, const float* __restrict__ bk,
    const float* __restrict__ bv,
    const int* __restrict__ ei, int* __restrict__ P,
    ushort_t* __restrict__ rank,
    ushort_t* __restrict__ qkv,
    int N, int E, int ntiles)
{
    // ---- histogram + rank prologue (the ONLY atomic pass) ----
    {
        int gtid   = (int)blockIdx.x * 384 + threadIdx.x;
        int stride = (int)gridDim.x * 384;
        for (int e = gtid; e < E; e += stride) {
            int d = ei[E + e];
            int old = atomicAdd(&P[d], 1);
            rank[e] = (ushort_t)old;
        }
    }

    __shared__ ushort_t sh[8320];     // 16640 B

    const int tid  = threadIdx.x;
    const int w    = tid >> 6;        // wave 0..5
    const int quad = (tid >> 4) & 3;
    const int l15  = tid & 15;
    const int colg = w << 6;          // col base 0..320

    // ---- load B fragments once: 16 x bf16x8 = 64 VGPRs ----
    bf16x8 bfr[4][4];
#pragma unroll
    for (int kt = 0; kt < 4; kt++)
#pragma unroll
        for (int cs = 0; cs < 4; cs++) {
            int col = colg + cs * 16 + l15;
            bfr[kt][cs] = *(const bf16x8*)&Wt[(size_t)col * 128 + kt * 32 + quad * 8];
        }

    const int mat = w >> 1;           // 0=Q,1=K,2=V
    const float* Bp = (mat == 0) ? bq : (mat == 1) ? bk : bv;
    float bias[4];
#pragma unroll
    for (int cs = 0; cs < 4; cs++)
        bias[cs] = Bp[((w & 1) << 6) + cs * 16 + l15];

    // ---- persistent loop over row tiles ----
    for (int tile = blockIdx.x; tile < ntiles; tile += gridDim.x) {
        const int row0 = tile * 64;
        __syncthreads();   // protect sh from previous iteration's readers

        // stage A: 64 rows x 128 k, bf16, k-packed [kc(16)][row(65 pad)][8]
        for (int ch = tid; ch < 1024; ch += 384) {
            int row = ch >> 4;
            int kc  = ch & 15;
            int grow = row0 + row; if (grow > N - 1) grow = N - 1;
            const float* xp = x + (size_t)grow * IN_DIM + kc * 8;
            float4 f0 = *(const float4*)xp;
            float4 f1 = *(const float4*)(xp + 4);
            union { ushort_t h[8]; uint4 u; } tt;
            tt.h[0] = f2bf(f0.x); tt.h[1] = f2bf(f0.y);
            tt.h[2] = f2bf(f0.z); tt.h[3] = f2bf(f0.w);
            tt.h[4] = f2bf(f1.x); tt.h[5] = f2bf(f1.y);
            tt.h[6] = f2bf(f1.z); tt.h[7] = f2bf(f1.w);
            *(uint4*)&sh[(kc * 65 + row) * 8] = tt.u;
        }
        __syncthreads();

        f32x4 acc[4][4];
#pragma unroll
        for (int r = 0; r < 4; r++)
#pragma unroll
            for (int cs = 0; cs < 4; cs++) acc[r][cs] = (f32x4){0.f, 0.f, 0.f, 0.f};

#pragma unroll
        for (int kt = 0; kt < 4; kt++) {
            int kc = kt * 4 + quad;
            bf16x8 af[4];
#pragma unroll
            for (int r = 0; r < 4; r++)
                af[r] = *(const bf16x8*)&sh[(kc * 65 + r * 16 + l15) * 8];
#pragma unroll
            for (int r = 0; r < 4; r++)
#pragma unroll
                for (int cs = 0; cs < 4; cs++)
                    acc[r][cs] = __builtin_amdgcn_mfma_f32_16x16x32_bf16(
                        af[r], bfr[kt][cs], acc[r][cs], 0, 0, 0);
        }

        // epilogue: bias + cvt, LDS transpose in 4 quarters of 16 rows
#define EPS 392
#pragma unroll
        for (int qq = 0; qq < 4; qq++) {
            __syncthreads();
            int lrow = quad << 2;
#pragma unroll
            for (int cs = 0; cs < 4; cs++) {
                int col = (w << 6) + cs * 16 + l15;
#pragma unroll
                for (int reg = 0; reg < 4; reg++)
                    sh[(lrow + reg) * EPS + col] = f2bf(acc[qq][cs][reg] + bias[cs]);
            }
            __syncthreads();
#pragma unroll
            for (int i = 0; i < 2; i++) {
                int c = tid + i * 384;
                int row = c / 48;
                int col = (c % 48) * 8;
                int grow = row0 + qq * 16 + row;
                if (grow < N) {
                    uint4 val = *(const uint4*)&sh[row * EPS + col];
                    *(uint4*)&qkv[(size_t)grow * QKVD + col] = val;
                }
            }
        }
#undef EPS
    }
}

// ---------------------------------------------------------------------------
// Single-pass exclusive scan over P[N] (decoupled lookback).
// P ends as exclusive bucket offsets and is NOT modified afterwards.
// ---------------------------------------------------------------------------
__global__ __launch_bounds__(1024) void scan_onepass(
    int* __restrict__ P, unsigned long long* __restrict__ desc, int N)
{
    __shared__ int sdata[1024];
    __shared__ int s_prefix;
    int b = blockIdx.x;
    int i = b * 1024 + threadIdx.x;
    int v = (i < N) ? P[i] : 0;
    sdata[threadIdx.x] = v;
    __syncthreads();
    for (int off = 1; off < 1024; off <<= 1) {
        int t = (threadIdx.x >= off) ? sdata[threadIdx.x - off] : 0;
        __syncthreads();
        sdata[threadIdx.x] += t;
        __syncthreads();
    }
    int incl  = sdata[threadIdx.x];
    int total = sdata[1023];

    if (threadIdx.x == 0) {
        unsigned long long st1 = ((unsigned long long)((b == 0) ? 2 : 1) << 32)
                                 | (uint_t)total;
        __hip_atomic_store(&desc[b], st1, __ATOMIC_RELEASE, __HIP_MEMORY_SCOPE_AGENT);
        int prefix = 0;
        if (b > 0) {
            int bb = b - 1;
            for (;;) {
                unsigned long long d = __hip_atomic_load(
                    &desc[bb], __ATOMIC_ACQUIRE, __HIP_MEMORY_SCOPE_AGENT);
                uint_t st = (uint_t)(d >> 32);
                if (st == 0) continue;
                prefix += (int)(uint_t)(d & 0xFFFFFFFFu);
                if (st == 2) break;
                bb--;
            }
            __hip_atomic_store(&desc[b],
                ((unsigned long long)2 << 32) | (uint_t)(prefix + total),
                __ATOMIC_RELEASE, __HIP_MEMORY_SCOPE_AGENT);
        }
        s_prefix = prefix;
    }
    __syncthreads();
    if (i < N) P[i] = s_prefix + incl - v;   // exclusive
}

// ---------------------------------------------------------------------------
// Atomic-free scatter: position = P[dst] (exclusive offset, read-only) +
// rank[e] (precomputed in gemm_rank's single atomic pass).
// ---------------------------------------------------------------------------
__global__ __launch_bounds__(256) void scatter(
    const int* __restrict__ ei, const int* __restrict__ P,
    const ushort_t* __restrict__ rank,
    int* __restrict__ sorted_src, int E)
{
    int e0 = (blockIdx.x * 256 + threadIdx.x) * 4;
    if (e0 + 4 <= E) {
        int4 s4 = *(const int4*)&ei[e0];
        int4 d4 = *(const int4*)&ei[E + e0];
        us4  r4 = *(const us4*)&rank[e0];
        sorted_src[P[d4.x] + (int)r4[0]] = s4.x;
        sorted_src[P[d4.y] + (int)r4[1]] = s4.y;
        sorted_src[P[d4.z] + (int)r4[2]] = s4.z;
        sorted_src[P[d4.w] + (int)r4[3]] = s4.w;
    } else {
        for (int e = e0; e < E; e++) {
            int pos = P[ei[E + e]] + (int)rank[e];
            sorted_src[pos] = ei[e];
        }
    }
}

// ---------------------------------------------------------------------------
// Segmented attention reduce + fused normalize. 16 lanes per node
// (4 nodes/wave): lane g holds dims [8g, 8g+8); one shfl_xor(1) per head dot.
// Segment bounds now come from the untouched exclusive offsets:
// [P[n], n+1<N ? P[n+1] : E).
// ---------------------------------------------------------------------------
__global__ __launch_bounds__(256) void segment_attn(
    const ushort_t* __restrict__ qkv,
    const int* __restrict__ P, const int* __restrict__ sorted_src,
    float* __restrict__ out, int N, int E)
{
    int n = (blockIdx.x * 256 + threadIdx.x) >> 4;
    int g = threadIdx.x & 15;
    if (n >= N) return;
    int start = P[n];
    int end   = (n + 1 < N) ? P[n + 1] : E;
    int deg   = end - start;

    const uint_t* qrow = (const uint_t*)(qkv + (size_t)n * QKVD);
    uint4 qu = *(const uint4*)(qrow + g * 4);
    float q0 = bf2f((ushort_t)(qu.x & 0xFFFF)), q1 = bf2f((ushort_t)(qu.x >> 16));
    float q2 = bf2f((ushort_t)(qu.y & 0xFFFF)), q3 = bf2f((ushort_t)(qu.y >> 16));
    float q4 = bf2f((ushort_t)(qu.z & 0xFFFF)), q5 = bf2f((ushort_t)(qu.z >> 16));
    float q6 = bf2f((ushort_t)(qu.w & 0xFFFF)), q7 = bf2f((ushort_t)(qu.w >> 16));

    float a0 = 0.f, a1 = 0.f, a2 = 0.f, a3 = 0.f;
    float a4 = 0.f, a5 = 0.f, a6 = 0.f, a7 = 0.f, z = 0.f;

    int myidx = (g < deg) ? sorted_src[start + g] : 0;
    int wbase = (threadIdx.x & 63) & 48;

#define PROC(ku, vu)                                                       \
    {                                                                      \
        float p = bf2f((ushort_t)((ku).x & 0xFFFF)) * q0                   \
                + bf2f((ushort_t)((ku).x >> 16))    * q1                   \
                + bf2f((ushort_t)((ku).y & 0xFFFF)) * q2                   \
                + bf2f((ushort_t)((ku).y >> 16))    * q3                   \
                + bf2f((ushort_t)((ku).z & 0xFFFF)) * q4                   \
                + bf2f((ushort_t)((ku).z >> 16))    * q5                   \
                + bf2f((ushort_t)((ku).w & 0xFFFF)) * q6                   \
                + bf2f((ushort_t)((ku).w >> 16))    * q7;                  \
        p += __shfl_xor(p, 1);                                             \
        p = fminf(fmaxf(p * 0.25f, -5.f), 5.f);                            \
        float s = __expf(p);                                               \
        a0 += bf2f((ushort_t)((vu).x & 0xFFFF)) * s;                       \
        a1 += bf2f((ushort_t)((vu).x >> 16))    * s;                       \
        a2 += bf2f((ushort_t)((vu).y & 0xFFFF)) * s;                       \
        a3 += bf2f((ushort_t)((vu).y >> 16))    * s;                       \
        a4 += bf2f((ushort_t)((vu).z & 0xFFFF)) * s;                       \
        a5 += bf2f((ushort_t)((vu).z >> 16))    * s;                       \
        a6 += bf2f((ushort_t)((vu).w & 0xFFFF)) * s;                       \
        a7 += bf2f((ushort_t)((vu).w >> 16))    * s;                       \
        z += s;                                                            \
    }

    int cnt = (deg < 16) ? deg : 16;
    int t = 0;
    for (; t + 2 <= cnt; t += 2) {
        int s0 = __shfl(myidx, wbase + t);
        int s1 = __shfl(myidx, wbase + t + 1);
        const uint_t* kv0 = (const uint_t*)(qkv + (size_t)s0 * QKVD + 128);
        const uint_t* kv1 = (const uint_t*)(qkv + (size_t)s1 * QKVD + 128);
        uint4 ku0 = *(const uint4*)(kv0 + g * 4);
        uint4 ku1 = *(const uint4*)(kv1 + g * 4);
        uint4 vu0 = *(const uint4*)(kv0 + 64 + g * 4);
        uint4 vu1 = *(const uint4*)(kv1 + 64 + g * 4);
        PROC(ku0, vu0); PROC(ku1, vu1);
    }
    if (t < cnt) {
        int s0 = __shfl(myidx, wbase + t);
        const uint_t* kv0 = (const uint_t*)(qkv + (size_t)s0 * QKVD + 128);
        uint4 ku0 = *(const uint4*)(kv0 + g * 4);
        uint4 vu0 = *(const uint4*)(kv0 + 64 + g * 4);
        PROC(ku0, vu0);
    }
    for (int j = start + 16; j < end; j++) {
        int s0 = sorted_src[j];
        const uint_t* kv0 = (const uint_t*)(qkv + (size_t)s0 * QKVD + 128);
        uint4 ku0 = *(const uint4*)(kv0 + g * 4);
        uint4 vu0 = *(const uint4*)(kv0 + 64 + g * 4);
        PROC(ku0, vu0);
    }
#undef PROC

    float inv = 1.f / (z + 1e-6f);
    float4 o0 = {a0 * inv, a1 * inv, a2 * inv, a3 * inv};
    float4 o1 = {a4 * inv, a5 * inv, a6 * inv, a7 * inv};
    float* ob = out + (size_t)n * OUTD + g * 8;
    *(float4*)ob = o0;
    *(float4*)(ob + 4) = o1;
}

extern "C" void kernel_launch(void* const* d_in, const int* in_sizes, int n_in,
                              void* d_out, int out_size, void* d_ws, size_t ws_size,
                              hipStream_t stream) {
    const float* x  = (const float*)d_in[0];
    const int*   ei = (const int*)d_in[1];
    const float* Wq = (const float*)d_in[4];
    const float* bq = (const float*)d_in[5];
    const float* Wk = (const float*)d_in[6];
    const float* bk = (const float*)d_in[7];
    const float* Wv = (const float*)d_in[8];
    const float* bv = (const float*)d_in[9];
    float* out = (float*)d_out;

    const int N = in_sizes[0] / IN_DIM;     // 100000
    const int E = in_sizes[1] / 2;          // 800000

    char* wsb = (char*)d_ws;
    ushort_t* qkv = (ushort_t*)wsb;                          // N*384 bf16
    ushort_t* Wt  = qkv + (size_t)N * QKVD;                  // 384*128 bf16
    int* P = (int*)(Wt + 384 * 128);                         // N ints
    unsigned long long* desc = (unsigned long long*)((char*)P + (size_t)N * 4);
    int* sorted = (int*)((char*)desc + 1024);                // E ints
    ushort_t* rank = (ushort_t*)(sorted + E);                // E ushorts

    const int ntiles = (N + 63) / 64;       // 1563
    const int NB     = (N + 1023) / 1024;   // 98 scan blocks

    prep_w<<<48, 256, 0, stream>>>(Wq, Wk, Wv, Wt, P, desc, N);
    gemm_rank<<<512, 384, 0, stream>>>(
        x, Wt, bq, bk, bv, ei, P, rank, qkv, N, E, ntiles);
    scan_onepass<<<NB, 1024, 0, stream>>>(P, desc, N);
    scatter<<<(E / 4 + 255) / 256, 256, 0, stream>>>(ei, P, rank, sorted, E);
    segment_attn<<<((size_t)N * 16 + 255) / 256, 256, 0, stream>>>(
        qkv, P, sorted, out, N, E);
}

// Round 2
// 272.401 us; speedup vs baseline: 1.1252x; 1.0443x over previous
//
#include <hip/hip_runtime.h>

#define IN_DIM   128
#define NH       8
#define HD       16
#define OUTD     128   // NH*HD
#define QKVD     384   // Q|K|V per node, bf16
#define SH       7     // coarse bucket = 128 nodes

typedef unsigned short ushort_t;
typedef unsigned int   uint_t;
typedef __bf16 bf16x8 __attribute__((ext_vector_type(8)));
typedef float  f32x4  __attribute__((ext_vector_type(4)));

__device__ __forceinline__ float bf2f(ushort_t u) {
    return __uint_as_float(((uint_t)u) << 16);
}
__device__ __forceinline__ ushort_t f2bf(float f) {
    uint_t u = __float_as_uint(f);
    u += 0x7FFFu + ((u >> 16) & 1u);      // RNE
    return (ushort_t)(u >> 16);
}

// ---------------------------------------------------------------------------
// prep_w: W[k][c] fp32 (3 mats) -> Wt[col][k] bf16, col in [0,384).
// Also zeroes desc[128] for the scan.
// ---------------------------------------------------------------------------
__global__ __launch_bounds__(256) void prep_w(
    const float* __restrict__ Wq, const float* __restrict__ Wk,
    const float* __restrict__ Wv, ushort_t* __restrict__ Wt,
    unsigned long long* __restrict__ desc)
{
    __shared__ float ld[32][33];
    int mat  = blockIdx.x >> 4;
    int tile = blockIdx.x & 15;
    int k0 = (tile >> 2) * 32, c0 = (tile & 3) * 32;
    const float* W = (mat == 0) ? Wq : (mat == 1) ? Wk : Wv;
    int t = threadIdx.x;
    {
        int k = t >> 3, c4 = (t & 7) * 4;
        float4 f = *(const float4*)&W[(size_t)(k0 + k) * 128 + c0 + c4];
        ld[k][c4 + 0] = f.x; ld[k][c4 + 1] = f.y;
        ld[k][c4 + 2] = f.z; ld[k][c4 + 3] = f.w;
    }
    __syncthreads();
    {
        int c = t >> 3, kg = (t & 7) * 4;
        union { ushort_t h[4]; uint2 u; } o;
        o.h[0] = f2bf(ld[kg + 0][c]); o.h[1] = f2bf(ld[kg + 1][c]);
        o.h[2] = f2bf(ld[kg + 2][c]); o.h[3] = f2bf(ld[kg + 3][c]);
        *(uint2*)&Wt[((size_t)(mat * 128 + c0 + c)) * 128 + k0 + kg] = o.u;
    }
    int t0 = blockIdx.x * 256 + threadIdx.x;
    if (t0 < 128) desc[t0] = 0ULL;
}

// ---------------------------------------------------------------------------
// ehist: 128 blocks. Coarse histogram (dst>>7) via LDS atomics only.
// Writes per-block histograms bin-major: Hf[bin*128 + blk].
// ---------------------------------------------------------------------------
__global__ __launch_bounds__(256) void ehist(
    const int* __restrict__ ei, int* __restrict__ Hf, int E, int NBC)
{
    __shared__ int lh[1024];
    for (int i = threadIdx.x; i < 1024; i += 256) lh[i] = 0;
    __syncthreads();
    int CH = (E + 127) >> 7;
    int e0 = blockIdx.x * CH;
    int e1 = min(E, e0 + CH);
    for (int e = e0 + threadIdx.x; e < e1; e += 256)
        atomicAdd(&lh[ei[E + e] >> SH], 1);
    __syncthreads();
    for (int b = threadIdx.x; b < NBC; b += 256)
        Hf[b * 128 + blockIdx.x] = lh[b];
}

// ---------------------------------------------------------------------------
// Single-pass exclusive scan (decoupled lookback) over Hf[NS], in place.
// ---------------------------------------------------------------------------
__global__ __launch_bounds__(1024) void scan_onepass(
    int* __restrict__ P, unsigned long long* __restrict__ desc, int N)
{
    __shared__ int sdata[1024];
    __shared__ int s_prefix;
    int b = blockIdx.x;
    int i = b * 1024 + threadIdx.x;
    int v = (i < N) ? P[i] : 0;
    sdata[threadIdx.x] = v;
    __syncthreads();
    for (int off = 1; off < 1024; off <<= 1) {
        int t = (threadIdx.x >= off) ? sdata[threadIdx.x - off] : 0;
        __syncthreads();
        sdata[threadIdx.x] += t;
        __syncthreads();
    }
    int incl  = sdata[threadIdx.x];
    int total = sdata[1023];

    if (threadIdx.x == 0) {
        unsigned long long st1 = ((unsigned long long)((b == 0) ? 2 : 1) << 32)
                                 | (uint_t)total;
        __hip_atomic_store(&desc[b], st1, __ATOMIC_RELEASE, __HIP_MEMORY_SCOPE_AGENT);
        int prefix = 0;
        if (b > 0) {
            int bb = b - 1;
            for (;;) {
                unsigned long long d = __hip_atomic_load(
                    &desc[bb], __ATOMIC_ACQUIRE, __HIP_MEMORY_SCOPE_AGENT);
                uint_t st = (uint_t)(d >> 32);
                if (st == 0) continue;
                prefix += (int)(uint_t)(d & 0xFFFFFFFFu);
                if (st == 2) break;
                bb--;
            }
            __hip_atomic_store(&desc[b],
                ((unsigned long long)2 << 32) | (uint_t)(prefix + total),
                __ATOMIC_RELEASE, __HIP_MEMORY_SCOPE_AGENT);
        }
        s_prefix = prefix;
    }
    __syncthreads();
    if (i < N) P[i] = s_prefix + incl - v;   // exclusive
}

// ---------------------------------------------------------------------------
// ebucket: 128 blocks. Re-read edges; LDS bins seeded from scanned bases give
// each edge its final coarse-bucket slot (LDS atomics only). Write packed
// record (fine<<20)|src.
// ---------------------------------------------------------------------------
__global__ __launch_bounds__(256) void ebucket(
    const int* __restrict__ ei, const int* __restrict__ S,
    uint_t* __restrict__ bkt, int E, int NBC)
{
    __shared__ int lb[1024];
    for (int b = threadIdx.x; b < NBC; b += 256)
        lb[b] = S[b * 128 + blockIdx.x];
    __syncthreads();
    int CH = (E + 127) >> 7;
    int e0 = blockIdx.x * CH;
    int e1 = min(E, e0 + CH);
    for (int e = e0 + threadIdx.x; e < e1; e += 256) {
        int d   = ei[E + e];
        int src = ei[e];
        int pos = atomicAdd(&lb[d >> SH], 1);
        bkt[pos] = (uint_t)src | ((uint_t)(d & 127) << 20);
    }
}

// ---------------------------------------------------------------------------
// efine: one block per coarse bucket (~1023 edges). 128-bin LDS histogram +
// LDS scan -> CSR offsets P[n] and fully sorted sorted_src. No global atomics.
// ---------------------------------------------------------------------------
__global__ __launch_bounds__(256) void efine(
    const uint_t* __restrict__ bkt, const int* __restrict__ S,
    int* __restrict__ P, int* __restrict__ sorted_src,
    int E, int N, int NBC)
{
    __shared__ int cnt[128];
    __shared__ int scn[128];
    int b    = blockIdx.x;
    int base = S[b * 128];
    int end  = (b + 1 < NBC) ? S[(b + 1) * 128] : E;
    int m    = end - base;
    if (threadIdx.x < 128) cnt[threadIdx.x] = 0;
    __syncthreads();
    for (int i = threadIdx.x; i < m; i += 256)
        atomicAdd(&cnt[bkt[base + i] >> 20], 1);
    __syncthreads();
    if (threadIdx.x < 128) scn[threadIdx.x] = cnt[threadIdx.x];
    __syncthreads();
    for (int off = 1; off < 128; off <<= 1) {
        int v = (threadIdx.x >= off && threadIdx.x < 128) ? scn[threadIdx.x - off] : 0;
        __syncthreads();
        if (threadIdx.x < 128) scn[threadIdx.x] += v;
        __syncthreads();
    }
    if (threadIdx.x < 128) {
        int excl = scn[threadIdx.x] - cnt[threadIdx.x];
        int n = b * 128 + threadIdx.x;
        if (n < N) P[n] = base + excl;
        cnt[threadIdx.x] = excl;           // reuse as running offset
    }
    __syncthreads();
    for (int i = threadIdx.x; i < m; i += 256) {
        uint_t r = bkt[base + i];
        int pos = atomicAdd(&cnt[r >> 20], 1);
        sorted_src[base + pos] = (int)(r & 0xFFFFFu);
    }
}

// ---------------------------------------------------------------------------
// gemm (persistent, pure): 512 blocks x 384 thr. Each wave holds its 16
// B-fragments (64 VGPRs); blocks grid-stride over 64-row tiles: stage A in
// LDS (k-packed, 65-pad), 64 MFMAs/wave, LDS-transpose epilogue -> coalesced
// dwordx4 stores to qkv[N][384] bf16.
// ---------------------------------------------------------------------------
__global__ __launch_bounds__(384, 3) void gemm(
    const float* __restrict__ x, const ushort_t* __restrict__ Wt,
    const float* __restrict__ bq, const float* __restrict__ bk,
    const float* __restrict__ bv,
    ushort_t* __restrict__ qkv,
    int N, int ntiles)
{
    __shared__ ushort_t sh[8320];     // 16640 B

    const int tid  = threadIdx.x;
    const int w    = tid >> 6;        // wave 0..5
    const int quad = (tid >> 4) & 3;
    const int l15  = tid & 15;
    const int colg = w << 6;          // col base 0..320

    // ---- load B fragments once: 16 x bf16x8 = 64 VGPRs ----
    bf16x8 bfr[4][4];
#pragma unroll
    for (int kt = 0; kt < 4; kt++)
#pragma unroll
        for (int cs = 0; cs < 4; cs++) {
            int col = colg + cs * 16 + l15;
            bfr[kt][cs] = *(const bf16x8*)&Wt[(size_t)col * 128 + kt * 32 + quad * 8];
        }

    const int mat = w >> 1;           // 0=Q,1=K,2=V
    const float* Bp = (mat == 0) ? bq : (mat == 1) ? bk : bv;
    float bias[4];
#pragma unroll
    for (int cs = 0; cs < 4; cs++)
        bias[cs] = Bp[((w & 1) << 6) + cs * 16 + l15];

    for (int tile = blockIdx.x; tile < ntiles; tile += gridDim.x) {
        const int row0 = tile * 64;
        __syncthreads();   // protect sh from previous iteration's readers

        // stage A: 64 rows x 128 k, bf16, k-packed [kc(16)][row(65 pad)][8]
        for (int ch = tid; ch < 1024; ch += 384) {
            int row = ch >> 4;
            int kc  = ch & 15;
            int grow = row0 + row; if (grow > N - 1) grow = N - 1;
            const float* xp = x + (size_t)grow * IN_DIM + kc * 8;
            float4 f0 = *(const float4*)xp;
            float4 f1 = *(const float4*)(xp + 4);
            union { ushort_t h[8]; uint4 u; } tt;
            tt.h[0] = f2bf(f0.x); tt.h[1] = f2bf(f0.y);
            tt.h[2] = f2bf(f0.z); tt.h[3] = f2bf(f0.w);
            tt.h[4] = f2bf(f1.x); tt.h[5] = f2bf(f1.y);
            tt.h[6] = f2bf(f1.z); tt.h[7] = f2bf(f1.w);
            *(uint4*)&sh[(kc * 65 + row) * 8] = tt.u;
        }
        __syncthreads();

        f32x4 acc[4][4];
#pragma unroll
        for (int r = 0; r < 4; r++)
#pragma unroll
            for (int cs = 0; cs < 4; cs++) acc[r][cs] = (f32x4){0.f, 0.f, 0.f, 0.f};

#pragma unroll
        for (int kt = 0; kt < 4; kt++) {
            int kc = kt * 4 + quad;
            bf16x8 af[4];
#pragma unroll
            for (int r = 0; r < 4; r++)
                af[r] = *(const bf16x8*)&sh[(kc * 65 + r * 16 + l15) * 8];
#pragma unroll
            for (int r = 0; r < 4; r++)
#pragma unroll
                for (int cs = 0; cs < 4; cs++)
                    acc[r][cs] = __builtin_amdgcn_mfma_f32_16x16x32_bf16(
                        af[r], bfr[kt][cs], acc[r][cs], 0, 0, 0);
        }

        // epilogue: bias + cvt, LDS transpose in 4 quarters of 16 rows
#define EPS 392
#pragma unroll
        for (int qq = 0; qq < 4; qq++) {
            __syncthreads();
            int lrow = quad << 2;
#pragma unroll
            for (int cs = 0; cs < 4; cs++) {
                int col = (w << 6) + cs * 16 + l15;
#pragma unroll
                for (int reg = 0; reg < 4; reg++)
                    sh[(lrow + reg) * EPS + col] = f2bf(acc[qq][cs][reg] + bias[cs]);
            }
            __syncthreads();
#pragma unroll
            for (int i = 0; i < 2; i++) {
                int c = tid + i * 384;
                int row = c / 48;
                int col = (c % 48) * 8;
                int grow = row0 + qq * 16 + row;
                if (grow < N) {
                    uint4 val = *(const uint4*)&sh[row * EPS + col];
                    *(uint4*)&qkv[(size_t)grow * QKVD + col] = val;
                }
            }
        }
#undef EPS
    }
}

// ---------------------------------------------------------------------------
// Segmented attention reduce + fused normalize. 16 lanes per node
// (4 nodes/wave). Segment bounds: [P[n], n+1<N ? P[n+1] : E).
// ---------------------------------------------------------------------------
__global__ __launch_bounds__(256) void segment_attn(
    const ushort_t* __restrict__ qkv,
    const int* __restrict__ P, const int* __restrict__ sorted_src,
    float* __restrict__ out, int N, int E)
{
    int n = (blockIdx.x * 256 + threadIdx.x) >> 4;
    int g = threadIdx.x & 15;
    if (n >= N) return;
    int start = P[n];
    int end   = (n + 1 < N) ? P[n + 1] : E;
    int deg   = end - start;

    const uint_t* qrow = (const uint_t*)(qkv + (size_t)n * QKVD);
    uint4 qu = *(const uint4*)(qrow + g * 4);
    float q0 = bf2f((ushort_t)(qu.x & 0xFFFF)), q1 = bf2f((ushort_t)(qu.x >> 16));
    float q2 = bf2f((ushort_t)(qu.y & 0xFFFF)), q3 = bf2f((ushort_t)(qu.y >> 16));
    float q4 = bf2f((ushort_t)(qu.z & 0xFFFF)), q5 = bf2f((ushort_t)(qu.z >> 16));
    float q6 = bf2f((ushort_t)(qu.w & 0xFFFF)), q7 = bf2f((ushort_t)(qu.w >> 16));

    float a0 = 0.f, a1 = 0.f, a2 = 0.f, a3 = 0.f;
    float a4 = 0.f, a5 = 0.f, a6 = 0.f, a7 = 0.f, z = 0.f;

    int myidx = (g < deg) ? sorted_src[start + g] : 0;
    int wbase = (threadIdx.x & 63) & 48;

#define PROC(ku, vu)                                                       \
    {                                                                      \
        float p = bf2f((ushort_t)((ku).x & 0xFFFF)) * q0                   \
                + bf2f((ushort_t)((ku).x >> 16))    * q1                   \
                + bf2f((ushort_t)((ku).y & 0xFFFF)) * q2                   \
                + bf2f((ushort_t)((ku).y >> 16))    * q3                   \
                + bf2f((ushort_t)((ku).z & 0xFFFF)) * q4                   \
                + bf2f((ushort_t)((ku).z >> 16))    * q5                   \
                + bf2f((ushort_t)((ku).w & 0xFFFF)) * q6                   \
                + bf2f((ushort_t)((ku).w >> 16))    * q7;                  \
        p += __shfl_xor(p, 1);                                             \
        p = fminf(fmaxf(p * 0.25f, -5.f), 5.f);                            \
        float s = __expf(p);                                               \
        a0 += bf2f((ushort_t)((vu).x & 0xFFFF)) * s;                       \
        a1 += bf2f((ushort_t)((vu).x >> 16))    * s;                       \
        a2 += bf2f((ushort_t)((vu).y & 0xFFFF)) * s;                       \
        a3 += bf2f((ushort_t)((vu).y >> 16))    * s;                       \
        a4 += bf2f((ushort_t)((vu).z & 0xFFFF)) * s;                       \
        a5 += bf2f((ushort_t)((vu).z >> 16))    * s;                       \
        a6 += bf2f((ushort_t)((vu).w & 0xFFFF)) * s;                       \
        a7 += bf2f((ushort_t)((vu).w >> 16))    * s;                       \
        z += s;                                                            \
    }

    int cnt = (deg < 16) ? deg : 16;
    int t = 0;
    for (; t + 2 <= cnt; t += 2) {
        int s0 = __shfl(myidx, wbase + t);
        int s1 = __shfl(myidx, wbase + t + 1);
        const uint_t* kv0 = (const uint_t*)(qkv + (size_t)s0 * QKVD + 128);
        const uint_t* kv1 = (const uint_t*)(qkv + (size_t)s1 * QKVD + 128);
        uint4 ku0 = *(const uint4*)(kv0 + g * 4);
        uint4 ku1 = *(const uint4*)(kv1 + g * 4);
        uint4 vu0 = *(const uint4*)(kv0 + 64 + g * 4);
        uint4 vu1 = *(const uint4*)(kv1 + 64 + g * 4);
        PROC(ku0, vu0); PROC(ku1, vu1);
    }
    if (t < cnt) {
        int s0 = __shfl(myidx, wbase + t);
        const uint_t* kv0 = (const uint_t*)(qkv + (size_t)s0 * QKVD + 128);
        uint4 ku0 = *(const uint4*)(kv0 + g * 4);
        uint4 vu0 = *(const uint4*)(kv0 + 64 + g * 4);
        PROC(ku0, vu0);
    }
    for (int j = start + 16; j < end; j++) {
        int s0 = sorted_src[j];
        const uint_t* kv0 = (const uint_t*)(qkv + (size_t)s0 * QKVD + 128);
        uint4 ku0 = *(const uint4*)(kv0 + g * 4);
        uint4 vu0 = *(const uint4*)(kv0 + 64 + g * 4);
        PROC(ku0, vu0);
    }
#undef PROC

    float inv = 1.f / (z + 1e-6f);
    float4 o0 = {a0 * inv, a1 * inv, a2 * inv, a3 * inv};
    float4 o1 = {a4 * inv, a5 * inv, a6 * inv, a7 * inv};
    float* ob = out + (size_t)n * OUTD + g * 8;
    *(float4*)ob = o0;
    *(float4*)(ob + 4) = o1;
}

extern "C" void kernel_launch(void* const* d_in, const int* in_sizes, int n_in,
                              void* d_out, int out_size, void* d_ws, size_t ws_size,
                              hipStream_t stream) {
    const float* x  = (const float*)d_in[0];
    const int*   ei = (const int*)d_in[1];
    const float* Wq = (const float*)d_in[4];
    const float* bq = (const float*)d_in[5];
    const float* Wk = (const float*)d_in[6];
    const float* bk = (const float*)d_in[7];
    const float* Wv = (const float*)d_in[8];
    const float* bv = (const float*)d_in[9];
    float* out = (float*)d_out;

    const int N = in_sizes[0] / IN_DIM;     // 100000
    const int E = in_sizes[1] / 2;          // 800000
    const int NBC = (N + 127) >> 7;         // 782 coarse buckets
    const int NS  = NBC * 128;              // scan length 100096

    char* wsb = (char*)d_ws;
    ushort_t* qkv = (ushort_t*)wsb;                          // N*384 bf16
    ushort_t* Wt  = qkv + (size_t)N * QKVD;                  // 384*128 bf16
    int* Hf = (int*)(Wt + 384 * 128);                        // NS ints
    unsigned long long* desc = (unsigned long long*)(Hf + NS);
    int* sorted = (int*)((char*)desc + 1024);                // E ints
    uint_t* bkt = (uint_t*)(sorted + E);                     // E uints
    int* P = (int*)(bkt + E);                                // N ints

    const int ntiles = (N + 63) / 64;       // 1563
    const int NB     = (NS + 1023) / 1024;  // 98 scan blocks

    prep_w<<<48, 256, 0, stream>>>(Wq, Wk, Wv, Wt, desc);
    ehist<<<128, 256, 0, stream>>>(ei, Hf, E, NBC);
    scan_onepass<<<NB, 1024, 0, stream>>>(Hf, desc, NS);
    ebucket<<<128, 256, 0, stream>>>(ei, Hf, bkt, E, NBC);
    efine<<<NBC, 256, 0, stream>>>(bkt, Hf, P, sorted, E, N, NBC);
    gemm<<<512, 384, 0, stream>>>(x, Wt, bq, bk, bv, qkv, N, ntiles);
    segment_attn<<<((size_t)N * 16 + 255) / 256, 256, 0, stream>>>(
        qkv, P, sorted, out, N, E);
}

// Round 4
// 248.781 us; speedup vs baseline: 1.2320x; 1.0949x over previous
//
#include <hip/hip_runtime.h>

#define IN_DIM   128
#define NH       8
#define HD       16
#define OUTD     128   // NH*HD
#define QKVD     384   // Q|K|V per node, bf16
#define SH       7     // coarse bucket = 128 nodes
#define NSORTB   64    // ebucketA blocks (private regions)

typedef unsigned short ushort_t;
typedef unsigned int   uint_t;
typedef __bf16 bf16x8 __attribute__((ext_vector_type(8)));
typedef float  f32x4  __attribute__((ext_vector_type(4)));

__device__ __forceinline__ float bf2f(ushort_t u) {
    return __uint_as_float(((uint_t)u) << 16);
}
__device__ __forceinline__ ushort_t f2bf(float f) {
    uint_t u = __float_as_uint(f);
    u += 0x7FFFu + ((u >> 16) & 1u);      // RNE
    return (ushort_t)(u >> 16);
}

// ---------------------------------------------------------------------------
// prep_w: W[k][c] fp32 (3 mats) -> Wt[col][k] bf16, col in [0,384).
// Also zeroes desc[128] for the scan.
// ---------------------------------------------------------------------------
__global__ __launch_bounds__(256) void prep_w(
    const float* __restrict__ Wq, const float* __restrict__ Wk,
    const float* __restrict__ Wv, ushort_t* __restrict__ Wt,
    unsigned long long* __restrict__ desc)
{
    __shared__ float ld[32][33];
    int mat  = blockIdx.x >> 4;
    int tile = blockIdx.x & 15;
    int k0 = (tile >> 2) * 32, c0 = (tile & 3) * 32;
    const float* W = (mat == 0) ? Wq : (mat == 1) ? Wk : Wv;
    int t = threadIdx.x;
    {
        int k = t >> 3, c4 = (t & 7) * 4;
        float4 f = *(const float4*)&W[(size_t)(k0 + k) * 128 + c0 + c4];
        ld[k][c4 + 0] = f.x; ld[k][c4 + 1] = f.y;
        ld[k][c4 + 2] = f.z; ld[k][c4 + 3] = f.w;
    }
    __syncthreads();
    {
        int c = t >> 3, kg = (t & 7) * 4;
        union { ushort_t h[4]; uint2 u; } o;
        o.h[0] = f2bf(ld[kg + 0][c]); o.h[1] = f2bf(ld[kg + 1][c]);
        o.h[2] = f2bf(ld[kg + 2][c]); o.h[3] = f2bf(ld[kg + 3][c]);
        *(uint2*)&Wt[((size_t)(mat * 128 + c0 + c)) * 128 + k0 + kg] = o.u;
    }
    int t0 = blockIdx.x * 256 + threadIdx.x;
    if (t0 < 128) desc[t0] = 0ULL;
}

// ---------------------------------------------------------------------------
// ebucketA: 64 blocks x 1024 thr, 1 chunk of ~12500 edges each. Full LDS
// counting sort of the chunk by coarse bin (dst>>7). Outputs:
//   Hf[bin*64+blk]  : per-(bin,block) count (bin-major, for global scan)
//   aux[bin*64+blk] : region-local start of bin's run (aux[NBC*64+blk]=m)
//   regions[blk*CH..]: chunk records (fine<<20)|src, sorted by bin —
//                      written 100% contiguously (no scattered globals).
// ---------------------------------------------------------------------------
__global__ __launch_bounds__(1024) void ebucketA(
    const int* __restrict__ ei, int* __restrict__ Hf, int* __restrict__ aux,
    uint_t* __restrict__ regions, int E, int NBC, int CH)
{
    __shared__ uint_t recs[12500];
    __shared__ int hist[1024];
    __shared__ int scn[1024];
    const int tid = threadIdx.x;
    const int blk = blockIdx.x;
    const int e0g = blk * CH;
    const int e1g = min(E, e0g + CH);
    const int m   = e1g - e0g;

    hist[tid] = 0;
    __syncthreads();
    for (int e = e0g + tid; e < e1g; e += 1024)
        atomicAdd(&hist[ei[E + e] >> SH], 1);
    __syncthreads();
    // per-(bin,block) counts for the global scan
    for (int b = tid; b < NBC; b += 1024)
        Hf[b * NSORTB + blk] = hist[b];
    // LDS inclusive scan over 1024 bins
    scn[tid] = hist[tid];
    __syncthreads();
    for (int off = 1; off < 1024; off <<= 1) {
        int v = (tid >= off) ? scn[tid - off] : 0;
        __syncthreads();
        scn[tid] += v;
        __syncthreads();
    }
    int excl = scn[tid] - hist[tid];
    if (tid < NBC) aux[tid * NSORTB + blk] = excl;
    if (tid == 0)  aux[NBC * NSORTB + blk] = m;
    hist[tid] = excl;                 // reuse as scatter cursor
    __syncthreads();
    // scatter records into LDS, sorted by bin
    for (int e = e0g + tid; e < e1g; e += 1024) {
        int d = ei[E + e];
        int src = ei[e];
        int slot = atomicAdd(&hist[d >> SH], 1);
        recs[slot] = (uint_t)src | ((uint_t)(d & 127) << 20);
    }
    __syncthreads();
    // stream chunk out contiguously
    for (int s = tid; s < m; s += 1024)
        regions[(size_t)blk * CH + s] = recs[s];
}

// ---------------------------------------------------------------------------
// scan4: single-pass exclusive scan (decoupled lookback), 4 elems/thread
// (int4). NS = NBC*64 -> 13 blocks, lookback depth <= 12.
// ---------------------------------------------------------------------------
__global__ __launch_bounds__(1024) void scan4(
    int* __restrict__ P, unsigned long long* __restrict__ desc, int NS)
{
    __shared__ int sdata[1024];
    __shared__ int s_prefix;
    int b  = blockIdx.x;
    int i0 = (b * 1024 + threadIdx.x) * 4;
    int4 v = {0, 0, 0, 0};
    if (i0 < NS) v = *(const int4*)&P[i0];    // NS % 4 == 0
    int s = v.x + v.y + v.z + v.w;
    sdata[threadIdx.x] = s;
    __syncthreads();
    for (int off = 1; off < 1024; off <<= 1) {
        int t = (threadIdx.x >= off) ? sdata[threadIdx.x - off] : 0;
        __syncthreads();
        sdata[threadIdx.x] += t;
        __syncthreads();
    }
    int incl  = sdata[threadIdx.x];
    int total = sdata[1023];

    if (threadIdx.x == 0) {
        unsigned long long st1 = ((unsigned long long)((b == 0) ? 2 : 1) << 32)
                                 | (uint_t)total;
        __hip_atomic_store(&desc[b], st1, __ATOMIC_RELEASE, __HIP_MEMORY_SCOPE_AGENT);
        int prefix = 0;
        if (b > 0) {
            int bb = b - 1;
            for (;;) {
                unsigned long long d = __hip_atomic_load(
                    &desc[bb], __ATOMIC_ACQUIRE, __HIP_MEMORY_SCOPE_AGENT);
                uint_t st = (uint_t)(d >> 32);
                if (st == 0) continue;
                prefix += (int)(uint_t)(d & 0xFFFFFFFFu);
                if (st == 2) break;
                bb--;
            }
            __hip_atomic_store(&desc[b],
                ((unsigned long long)2 << 32) | (uint_t)(prefix + total),
                __ATOMIC_RELEASE, __HIP_MEMORY_SCOPE_AGENT);
        }
        s_prefix = prefix;
    }
    __syncthreads();
    if (i0 < NS) {
        int base = s_prefix + incl - s;        // exclusive
        int4 o;
        o.x = base;
        o.y = base + v.x;
        o.z = base + v.x + v.y;
        o.w = base + v.x + v.y + v.z;
        *(int4*)&P[i0] = o;
    }
}

// ---------------------------------------------------------------------------
// efine: one block per coarse bucket. Gathers the bucket's 64 runs from the
// private regions (coalesced 4-lane bursts), fine-sorts by (dst&127) in LDS,
// writes P[n] and sorted_src fully coalesced. No scattered global writes.
// ---------------------------------------------------------------------------
__global__ __launch_bounds__(256) void efine(
    const uint_t* __restrict__ regions, const int* __restrict__ aux,
    const int* __restrict__ S,
    int* __restrict__ P, int* __restrict__ sorted_src,
    int N, int NBC, int CH)
{
    __shared__ int rl[64], ro[64], doff[64];
    __shared__ int cnt[128], scn2[128];
    __shared__ uint_t stage[4096];
    __shared__ int    sst[4096];
    const int tid = threadIdx.x;
    const int b   = blockIdx.x;
    const int base = S[b * NSORTB];

    if (tid < 64) {
        int r0 = aux[b * NSORTB + tid];
        int r1 = aux[(b + 1) * NSORTB + tid];
        ro[tid] = r0;
        rl[tid] = r1 - r0;
        doff[tid] = r1 - r0;
    }
    __syncthreads();
    for (int off = 1; off < 64; off <<= 1) {
        int v = (tid >= off && tid < 64) ? doff[tid - off] : 0;
        __syncthreads();
        if (tid < 64) doff[tid] += v;
        __syncthreads();
    }
    const int m = doff[63];

    // gather runs: r = tid>>2 (64 regions), k = tid&3 -> 4-lane coalesced
    {
        int r = tid >> 2, k = tid & 3;
        int dst0 = doff[r] - rl[r];
        int src0 = ro[r];
        int len  = rl[r];
        for (int i = k; i < len; i += 4)
            stage[dst0 + i] = regions[(size_t)r * CH + src0 + i];
    }
    __syncthreads();

    // fine histogram over 128 node slots
    if (tid < 128) cnt[tid] = 0;
    __syncthreads();
    for (int i = tid; i < m; i += 256)
        atomicAdd(&cnt[stage[i] >> 20], 1);
    __syncthreads();
    if (tid < 128) scn2[tid] = cnt[tid];
    __syncthreads();
    for (int off = 1; off < 128; off <<= 1) {
        int v = (tid >= off && tid < 128) ? scn2[tid - off] : 0;
        __syncthreads();
        if (tid < 128) scn2[tid] += v;
        __syncthreads();
    }
    if (tid < 128) {
        int excl = scn2[tid] - cnt[tid];
        int n = b * 128 + tid;
        if (n < N) P[n] = base + excl;
        cnt[tid] = excl;               // reuse as cursor
    }
    __syncthreads();
    for (int i = tid; i < m; i += 256) {
        uint_t r = stage[i];
        int pos = atomicAdd(&cnt[r >> 20], 1);
        sst[pos] = (int)(r & 0xFFFFFu);
    }
    __syncthreads();
    for (int i = tid; i < m; i += 256)
        sorted_src[base + i] = sst[i];
}

// ---------------------------------------------------------------------------
// gemm (persistent, pure): 512 blocks x 384 thr. Each wave holds its 16
// B-fragments (64 VGPRs); blocks grid-stride over 64-row tiles: stage A in
// LDS (k-packed, 65-pad), 64 MFMAs/wave, LDS-transpose epilogue -> coalesced
// dwordx4 stores to qkv[N][384] bf16.
// ---------------------------------------------------------------------------
__global__ __launch_bounds__(384, 3) void gemm(
    const float* __restrict__ x, const ushort_t* __restrict__ Wt,
    const float* __restrict__ bq, const float* __restrict__ bk,
    const float* __restrict__ bv,
    ushort_t* __restrict__ qkv,
    int N, int ntiles)
{
    __shared__ ushort_t sh[8320];     // 16640 B

    const int tid  = threadIdx.x;
    const int w    = tid >> 6;        // wave 0..5
    const int quad = (tid >> 4) & 3;
    const int l15  = tid & 15;
    const int colg = w << 6;          // col base 0..320

    bf16x8 bfr[4][4];
#pragma unroll
    for (int kt = 0; kt < 4; kt++)
#pragma unroll
        for (int cs = 0; cs < 4; cs++) {
            int col = colg + cs * 16 + l15;
            bfr[kt][cs] = *(const bf16x8*)&Wt[(size_t)col * 128 + kt * 32 + quad * 8];
        }

    const int mat = w >> 1;           // 0=Q,1=K,2=V
    const float* Bp = (mat == 0) ? bq : (mat == 1) ? bk : bv;
    float bias[4];
#pragma unroll
    for (int cs = 0; cs < 4; cs++)
        bias[cs] = Bp[((w & 1) << 6) + cs * 16 + l15];

    for (int tile = blockIdx.x; tile < ntiles; tile += gridDim.x) {
        const int row0 = tile * 64;
        __syncthreads();

        for (int ch = tid; ch < 1024; ch += 384) {
            int row = ch >> 4;
            int kc  = ch & 15;
            int grow = row0 + row; if (grow > N - 1) grow = N - 1;
            const float* xp = x + (size_t)grow * IN_DIM + kc * 8;
            float4 f0 = *(const float4*)xp;
            float4 f1 = *(const float4*)(xp + 4);
            union { ushort_t h[8]; uint4 u; } tt;
            tt.h[0] = f2bf(f0.x); tt.h[1] = f2bf(f0.y);
            tt.h[2] = f2bf(f0.z); tt.h[3] = f2bf(f0.w);
            tt.h[4] = f2bf(f1.x); tt.h[5] = f2bf(f1.y);
            tt.h[6] = f2bf(f1.z); tt.h[7] = f2bf(f1.w);
            *(uint4*)&sh[(kc * 65 + row) * 8] = tt.u;
        }
        __syncthreads();

        f32x4 acc[4][4];
#pragma unroll
        for (int r = 0; r < 4; r++)
#pragma unroll
            for (int cs = 0; cs < 4; cs++) acc[r][cs] = (f32x4){0.f, 0.f, 0.f, 0.f};

#pragma unroll
        for (int kt = 0; kt < 4; kt++) {
            int kc = kt * 4 + quad;
            bf16x8 af[4];
#pragma unroll
            for (int r = 0; r < 4; r++)
                af[r] = *(const bf16x8*)&sh[(kc * 65 + r * 16 + l15) * 8];
#pragma unroll
            for (int r = 0; r < 4; r++)
#pragma unroll
                for (int cs = 0; cs < 4; cs++)
                    acc[r][cs] = __builtin_amdgcn_mfma_f32_16x16x32_bf16(
                        af[r], bfr[kt][cs], acc[r][cs], 0, 0, 0);
        }

#define EPS 392
#pragma unroll
        for (int qq = 0; qq < 4; qq++) {
            __syncthreads();
            int lrow = quad << 2;
#pragma unroll
            for (int cs = 0; cs < 4; cs++) {
                int col = (w << 6) + cs * 16 + l15;
#pragma unroll
                for (int reg = 0; reg < 4; reg++)
                    sh[(lrow + reg) * EPS + col] = f2bf(acc[qq][cs][reg] + bias[cs]);
            }
            __syncthreads();
#pragma unroll
            for (int i = 0; i < 2; i++) {
                int c = tid + i * 384;
                int row = c / 48;
                int col = (c % 48) * 8;
                int grow = row0 + qq * 16 + row;
                if (grow < N) {
                    uint4 val = *(const uint4*)&sh[row * EPS + col];
                    *(uint4*)&qkv[(size_t)grow * QKVD + col] = val;
                }
            }
        }
#undef EPS
    }
}

// ---------------------------------------------------------------------------
// Segmented attention reduce + fused normalize. 16 lanes per node
// (4 nodes/wave). 4-edge unrolled main loop (8 loads in flight);
// nontemporal out stores (51 MB streamed, never re-read).
// ---------------------------------------------------------------------------
__global__ __launch_bounds__(256) void segment_attn(
    const ushort_t* __restrict__ qkv,
    const int* __restrict__ P, const int* __restrict__ sorted_src,
    float* __restrict__ out, int N, int E)
{
    int n = (blockIdx.x * 256 + threadIdx.x) >> 4;
    int g = threadIdx.x & 15;
    if (n >= N) return;
    int start = P[n];
    int end   = (n + 1 < N) ? P[n + 1] : E;
    int deg   = end - start;

    const uint_t* qrow = (const uint_t*)(qkv + (size_t)n * QKVD);
    uint4 qu = *(const uint4*)(qrow + g * 4);
    float q0 = bf2f((ushort_t)(qu.x & 0xFFFF)), q1 = bf2f((ushort_t)(qu.x >> 16));
    float q2 = bf2f((ushort_t)(qu.y & 0xFFFF)), q3 = bf2f((ushort_t)(qu.y >> 16));
    float q4 = bf2f((ushort_t)(qu.z & 0xFFFF)), q5 = bf2f((ushort_t)(qu.z >> 16));
    float q6 = bf2f((ushort_t)(qu.w & 0xFFFF)), q7 = bf2f((ushort_t)(qu.w >> 16));

    float a0 = 0.f, a1 = 0.f, a2 = 0.f, a3 = 0.f;
    float a4 = 0.f, a5 = 0.f, a6 = 0.f, a7 = 0.f, z = 0.f;

    int myidx = (g < deg) ? sorted_src[start + g] : 0;
    int wbase = (threadIdx.x & 63) & 48;

#define PROC(ku, vu)                                                       \
    {                                                                      \
        float p = bf2f((ushort_t)((ku).x & 0xFFFF)) * q0                   \
                + bf2f((ushort_t)((ku).x >> 16))    * q1                   \
                + bf2f((ushort_t)((ku).y & 0xFFFF)) * q2                   \
                + bf2f((ushort_t)((ku).y >> 16))    * q3                   \
                + bf2f((ushort_t)((ku).z & 0xFFFF)) * q4                   \
                + bf2f((ushort_t)((ku).z >> 16))    * q5                   \
                + bf2f((ushort_t)((ku).w & 0xFFFF)) * q6                   \
                + bf2f((ushort_t)((ku).w >> 16))    * q7;                  \
        p += __shfl_xor(p, 1);                                             \
        p = fminf(fmaxf(p * 0.25f, -5.f), 5.f);                            \
        float s = __expf(p);                                               \
        a0 += bf2f((ushort_t)((vu).x & 0xFFFF)) * s;                       \
        a1 += bf2f((ushort_t)((vu).x >> 16))    * s;                       \
        a2 += bf2f((ushort_t)((vu).y & 0xFFFF)) * s;                       \
        a3 += bf2f((ushort_t)((vu).y >> 16))    * s;                       \
        a4 += bf2f((ushort_t)((vu).z & 0xFFFF)) * s;                       \
        a5 += bf2f((ushort_t)((vu).z >> 16))    * s;                       \
        a6 += bf2f((ushort_t)((vu).w & 0xFFFF)) * s;                       \
        a7 += bf2f((ushort_t)((vu).w >> 16))    * s;                       \
        z += s;                                                            \
    }

    int cnt = (deg < 16) ? deg : 16;
    int t = 0;
    for (; t + 4 <= cnt; t += 4) {
        int s0 = __shfl(myidx, wbase + t);
        int s1 = __shfl(myidx, wbase + t + 1);
        int s2 = __shfl(myidx, wbase + t + 2);
        int s3 = __shfl(myidx, wbase + t + 3);
        const uint_t* kv0 = (const uint_t*)(qkv + (size_t)s0 * QKVD + 128);
        const uint_t* kv1 = (const uint_t*)(qkv + (size_t)s1 * QKVD + 128);
        const uint_t* kv2 = (const uint_t*)(qkv + (size_t)s2 * QKVD + 128);
        const uint_t* kv3 = (const uint_t*)(qkv + (size_t)s3 * QKVD + 128);
        uint4 ku0 = *(const uint4*)(kv0 + g * 4);
        uint4 ku1 = *(const uint4*)(kv1 + g * 4);
        uint4 ku2 = *(const uint4*)(kv2 + g * 4);
        uint4 ku3 = *(const uint4*)(kv3 + g * 4);
        uint4 vu0 = *(const uint4*)(kv0 + 64 + g * 4);
        uint4 vu1 = *(const uint4*)(kv1 + 64 + g * 4);
        uint4 vu2 = *(const uint4*)(kv2 + 64 + g * 4);
        uint4 vu3 = *(const uint4*)(kv3 + 64 + g * 4);
        PROC(ku0, vu0); PROC(ku1, vu1); PROC(ku2, vu2); PROC(ku3, vu3);
    }
    for (; t + 2 <= cnt; t += 2) {
        int s0 = __shfl(myidx, wbase + t);
        int s1 = __shfl(myidx, wbase + t + 1);
        const uint_t* kv0 = (const uint_t*)(qkv + (size_t)s0 * QKVD + 128);
        const uint_t* kv1 = (const uint_t*)(qkv + (size_t)s1 * QKVD + 128);
        uint4 ku0 = *(const uint4*)(kv0 + g * 4);
        uint4 ku1 = *(const uint4*)(kv1 + g * 4);
        uint4 vu0 = *(const uint4*)(kv0 + 64 + g * 4);
        uint4 vu1 = *(const uint4*)(kv1 + 64 + g * 4);
        PROC(ku0, vu0); PROC(ku1, vu1);
    }
    if (t < cnt) {
        int s0 = __shfl(myidx, wbase + t);
        const uint_t* kv0 = (const uint_t*)(qkv + (size_t)s0 * QKVD + 128);
        uint4 ku0 = *(const uint4*)(kv0 + g * 4);
        uint4 vu0 = *(const uint4*)(kv0 + 64 + g * 4);
        PROC(ku0, vu0);
    }
    for (int j = start + 16; j + 2 <= end; j += 2) {
        int s0 = sorted_src[j];
        int s1 = sorted_src[j + 1];
        const uint_t* kv0 = (const uint_t*)(qkv + (size_t)s0 * QKVD + 128);
        const uint_t* kv1 = (const uint_t*)(qkv + (size_t)s1 * QKVD + 128);
        uint4 ku0 = *(const uint4*)(kv0 + g * 4);
        uint4 ku1 = *(const uint4*)(kv1 + g * 4);
        uint4 vu0 = *(const uint4*)(kv0 + 64 + g * 4);
        uint4 vu1 = *(const uint4*)(kv1 + 64 + g * 4);
        PROC(ku0, vu0); PROC(ku1, vu1);
    }
    if (deg > 16 && ((deg - 16) & 1)) {
        int s0 = sorted_src[end - 1];
        const uint_t* kv0 = (const uint_t*)(qkv + (size_t)s0 * QKVD + 128);
        uint4 ku0 = *(const uint4*)(kv0 + g * 4);
        uint4 vu0 = *(const uint4*)(kv0 + 64 + g * 4);
        PROC(ku0, vu0);
    }
#undef PROC

    float inv = 1.f / (z + 1e-6f);
    f32x4 o0 = {a0 * inv, a1 * inv, a2 * inv, a3 * inv};
    f32x4 o1 = {a4 * inv, a5 * inv, a6 * inv, a7 * inv};
    float* ob = out + (size_t)n * OUTD + g * 8;
    __builtin_nontemporal_store(o0, (f32x4*)ob);
    __builtin_nontemporal_store(o1, (f32x4*)(ob + 4));
}

extern "C" void kernel_launch(void* const* d_in, const int* in_sizes, int n_in,
                              void* d_out, int out_size, void* d_ws, size_t ws_size,
                              hipStream_t stream) {
    const float* x  = (const float*)d_in[0];
    const int*   ei = (const int*)d_in[1];
    const float* Wq = (const float*)d_in[4];
    const float* bq = (const float*)d_in[5];
    const float* Wk = (const float*)d_in[6];
    const float* bk = (const float*)d_in[7];
    const float* Wv = (const float*)d_in[8];
    const float* bv = (const float*)d_in[9];
    float* out = (float*)d_out;

    const int N = in_sizes[0] / IN_DIM;     // 100000
    const int E = in_sizes[1] / 2;          // 800000
    const int NBC = (N + 127) >> 7;         // 782 coarse buckets
    const int NS  = NBC * NSORTB;           // 50048 scan elements
    const int CH  = (E + NSORTB - 1) / NSORTB;   // 12500 edges/region

    char* wsb = (char*)d_ws;
    ushort_t* qkv = (ushort_t*)wsb;                          // N*384 bf16
    ushort_t* Wt  = qkv + (size_t)N * QKVD;                  // 384*128 bf16
    int* Hf = (int*)(Wt + 384 * 128);                        // NS ints
    unsigned long long* desc = (unsigned long long*)(Hf + NS);
    int* aux = (int*)((char*)desc + 1024);                   // (NBC+1)*64 ints
    uint_t* regions = (uint_t*)(aux + (NBC + 1) * NSORTB);   // E uints
    int* sorted = (int*)(regions + (size_t)NSORTB * CH);     // E ints
    int* P = sorted + E;                                     // N ints

    const int ntiles = (N + 63) / 64;       // 1563
    const int NSB    = (NS + 4095) / 4096;  // 13 scan blocks

    prep_w<<<48, 256, 0, stream>>>(Wq, Wk, Wv, Wt, desc);
    ebucketA<<<NSORTB, 1024, 0, stream>>>(ei, Hf, aux, regions, E, NBC, CH);
    scan4<<<NSB, 1024, 0, stream>>>(Hf, desc, NS);
    efine<<<NBC, 256, 0, stream>>>(regions, aux, Hf, P, sorted, N, NBC, CH);
    gemm<<<512, 384, 0, stream>>>(x, Wt, bq, bk, bv, qkv, N, ntiles);
    segment_attn<<<((size_t)N * 16 + 255) / 256, 256, 0, stream>>>(
        qkv, P, sorted, out, N, E);
}